// Round 14
// baseline (297.763 us; speedup 1.0000x reference)
//
#include <hip/hip_runtime.h>
#include <hip/hip_bf16.h>
#include <math.h>

#define NN 4096
#define CD 768
#define HD 512
#define OD 50
#define FGD 818   // CD + OD

typedef short short8 __attribute__((ext_vector_type(8)));
typedef _Float16 half8 __attribute__((ext_vector_type(8)));
typedef float f32x4 __attribute__((ext_vector_type(4)));
typedef unsigned short us4 __attribute__((ext_vector_type(4)));
typedef unsigned short ushortT;
typedef unsigned char uchar;
typedef unsigned long long u64;

__device__ inline ushortT f2bf(float v) {
    __hip_bfloat16 b = __float2bfloat16(v);
    return *(ushortT*)&b;
}
__device__ inline float bf2f(ushortT u) {
    __hip_bfloat16 b = *(__hip_bfloat16*)&u;
    return __bfloat162float(b);
}
__device__ inline float dinv_of(int d) {
    return (float)(1.0 / sqrt((double)(1 + d)));
}

// ---------------------------------------------------------------------------
// K0b: threshold scalars. scal[0] = 2*S0.S1, scal[1] = 2*n0*n1.
// ---------------------------------------------------------------------------
__global__ __launch_bounds__(256) void gdot_kernel(const double* __restrict__ gsum,
                                                   const int* __restrict__ labels,
                                                   double* __restrict__ scal) {
    int t = threadIdx.x;
    double d = 0.0;
    for (int c = t; c < CD; c += 256) d += gsum[c] * gsum[768 + c];
    int n0 = 0;
    for (int i = t; i < NN; i += 256) n0 += (labels[i] == 0) ? 1 : 0;
    for (int off = 32; off; off >>= 1) {
        d += __shfl_down(d, off);
        n0 += __shfl_down(n0, off);
    }
    __shared__ double sd[4];
    __shared__ int sn[4];
    int wid = t >> 6, lane = t & 63;
    if (lane == 0) { sd[wid] = d; sn[wid] = n0; }
    __syncthreads();
    if (t == 0) {
        double D = sd[0] + sd[1] + sd[2] + sd[3];
        double N0 = (double)(sn[0] + sn[1] + sn[2] + sn[3]);
        scal[0] = 2.0 * D;
        scal[1] = 2.0 * N0 * ((double)NN - N0);
    }
}

// ---------------------------------------------------------------------------
// SIMK4: sim (R6/R8-proven staging) fused with K4 = x@W1 transpose-out,
// R13: K4 output now BF16 (xw1b, 4 MB) — halves K5's B-operand stream.
// ---------------------------------------------------------------------------
#define BAND 0.10
#define RC_CAP (1 << 18)
#define RCB 256

__global__ __launch_bounds__(256) void simk4(
    const ushortT* __restrict__ xf, const ushortT* __restrict__ xh,
    const ushortT* __restrict__ w1t, const int* __restrict__ labels,
    const double* __restrict__ scal, u64* __restrict__ abbits,
    float* __restrict__ lm, int* __restrict__ deg,
    int* __restrict__ rc_cnt, int* __restrict__ rc_list,
    ushortT* __restrict__ xw1b) {
    __shared__ ushortT lds[2 * 64 * 72];    // 18432 B staging / flags
    __shared__ int larr[128];
    __shared__ int rcbuf[RCB];
    __shared__ int rcn, rcbase;
    int tid = threadIdx.x;
    int lane = tid & 63;
    int w = tid >> 6;
    int wr = w >> 1, wc = w & 1;
    int m = lane & 15, quad = lane >> 4;

    if (blockIdx.x >= 2080) {
        // ---------------- K4 branch: xw1b^T = bf16((x @ W1)^T) ----------------
        int idx = blockIdx.x - 2080;
        int row0 = (idx >> 3) * 64, col0 = (idx & 7) * 64;
        f32x4 acc[2][2] = {{{0.f, 0.f, 0.f, 0.f}, {0.f, 0.f, 0.f, 0.f}},
                           {{0.f, 0.f, 0.f, 0.f}, {0.f, 0.f, 0.f, 0.f}}};
        for (int k0 = 0; k0 < CD; k0 += 64) {
#pragma unroll
            for (int t = 0; t < 2; ++t) {
                int id2 = tid + t * 256;
                int row = id2 >> 3, c8 = (id2 & 7) * 8;
                *(short8*)&lds[row * 72 + c8] =
                    *(const short8*)&xh[(size_t)(row0 + row) * CD + k0 + c8];
                *(short8*)&lds[4608 + row * 72 + c8] =
                    *(const short8*)&w1t[(size_t)(col0 + row) * CD + k0 + c8];
            }
            __syncthreads();
#pragma unroll
            for (int ks = 0; ks < 2; ++ks) {
                short8 af[2], bf[2];
#pragma unroll
                for (int i = 0; i < 2; ++i)
                    af[i] = *(const short8*)&lds[(wr * 32 + i * 16 + m) * 72 +
                                                 ks * 32 + quad * 8];
#pragma unroll
                for (int j = 0; j < 2; ++j)
                    bf[j] = *(const short8*)&lds[4608 +
                                                 (wc * 32 + j * 16 + m) * 72 +
                                                 ks * 32 + quad * 8];
#pragma unroll
                for (int i = 0; i < 2; ++i)
#pragma unroll
                    for (int j = 0; j < 2; ++j)
                        acc[i][j] = __builtin_amdgcn_mfma_f32_16x16x32_bf16(
                            af[i], bf[j], acc[i][j], 0, 0, 0);
            }
            __syncthreads();
        }
#pragma unroll
        for (int i = 0; i < 2; ++i)
#pragma unroll
            for (int j = 0; j < 2; ++j) {
                int row = row0 + wr * 32 + i * 16 + quad * 4;
                int col = col0 + wc * 32 + j * 16 + m;
                us4 o;
                o[0] = f2bf(acc[i][j][0]);
                o[1] = f2bf(acc[i][j][1]);
                o[2] = f2bf(acc[i][j][2]);
                o[3] = f2bf(acc[i][j][3]);
                *(us4*)&xw1b[(size_t)col * NN + row] = o;
            }
        return;
    }

    // ------------------------- sim branch -------------------------
    // super-tile + XCD-chunked mapping (2080 = 8 XCD chunks x 260)
    int bid = blockIdx.x;
    int sid = (bid & 7) * 260 + (bid >> 3);   // bijective; xcd gets contig sids
    int sby = 0, rem = sid;
    for (; sby < 8; ++sby) {
        int rowsz = 36 + (7 - sby) * 64;      // diag ST (36) + off-diag STs (64)
        if (rem < rowsz) break;
        rem -= rowsz;
    }
    int sbx, iby, ibx;
    if (rem < 36) {                            // diagonal super-tile (8x8 tri)
        sbx = sby;
        iby = 0;
        while (rem >= 8 - iby) { rem -= 8 - iby; ++iby; }
        ibx = iby + rem;
    } else {                                   // off-diagonal super-tiles
        rem -= 36;
        sbx = sby + 1 + (rem >> 6);
        int u = rem & 63;
        iby = u >> 3; ibx = u & 7;
    }
    int by = sby * 8 + iby, bx = sbx * 8 + ibx;
    bool diag = (bx == by);
    int row0 = by * 64, col0 = bx * 64;

    if (tid == 0) rcn = 0;
    if (tid < 64) larr[tid] = labels[row0 + tid];
    else if (tid < 128) larr[tid] = labels[col0 + tid - 64];

    f32x4 acc[2][2] = {{{0.f, 0.f, 0.f, 0.f}, {0.f, 0.f, 0.f, 0.f}},
                       {{0.f, 0.f, 0.f, 0.f}, {0.f, 0.f, 0.f, 0.f}}};

    const size_t rowbase = (size_t)row0 * CD;
    const size_t colbase = (size_t)col0 * CD;
    short8 rg[2][2];
#pragma unroll
    for (int tt = 0; tt < 2; ++tt) {
        int id2 = tid + tt * 256;
        int row = id2 >> 3, c8 = (id2 & 7) * 8;
        rg[tt][0] = *(const short8*)&xf[rowbase + (size_t)row * CD + c8];
        rg[tt][1] = *(const short8*)&xf[colbase + (size_t)row * CD + c8];
    }

    for (int k0 = 0; k0 < CD; k0 += 64) {
        __syncthreads();                       // prev compute done; LDS free
#pragma unroll
        for (int tt = 0; tt < 2; ++tt) {
            int id2 = tid + tt * 256;
            int row = id2 >> 3, c8 = (id2 & 7) * 8;
            *(short8*)&lds[0 * 4608 + row * 72 + c8] = rg[tt][0];
            *(short8*)&lds[1 * 4608 + row * 72 + c8] = rg[tt][1];
        }
        __syncthreads();
        if (k0 + 64 < CD) {                    // prefetch next K-step early
#pragma unroll
            for (int tt = 0; tt < 2; ++tt) {
                int id2 = tid + tt * 256;
                int row = id2 >> 3, c8 = (id2 & 7) * 8 + k0 + 64;
                rg[tt][0] = *(const short8*)&xf[rowbase + (size_t)row * CD + c8];
                rg[tt][1] = *(const short8*)&xf[colbase + (size_t)row * CD + c8];
            }
        }
#pragma unroll
        for (int ks = 0; ks < 2; ++ks) {
            half8 ah[2], bh[2];
#pragma unroll
            for (int i = 0; i < 2; ++i)
                ah[i] = *(const half8*)&lds[(wr * 32 + i * 16 + m) * 72 +
                                            ks * 32 + quad * 8];
#pragma unroll
            for (int j = 0; j < 2; ++j)
                bh[j] = *(const half8*)&lds[4608 + (wc * 32 + j * 16 + m) * 72 +
                                            ks * 32 + quad * 8];
#pragma unroll
            for (int i = 0; i < 2; ++i)
#pragma unroll
                for (int j = 0; j < 2; ++j)
                    acc[i][j] = __builtin_amdgcn_mfma_f32_16x16x32_f16(
                        ah[i], bh[j], acc[i][j], 0, 0, 0);
        }
    }
    __syncthreads();                           // before flags alias LDS

    // ---- edge flags (alias staging LDS); band entries -> LDS buffer ----
    double thrd;
    {
        double cnt = scal[1];
        thrd = (cnt > 0.0) ? (scal[0] / cnt) : 0.0;
    }
    uchar* flags = (uchar*)lds;             // [64][68]
#pragma unroll
    for (int i = 0; i < 2; ++i)
#pragma unroll
        for (int j = 0; j < 2; ++j) {
#pragma unroll
            for (int r = 0; r < 4; ++r) {
                int row = wr * 32 + i * 16 + quad * 4 + r;
                int col = wc * 32 + j * 16 + m;
                bool same = (larr[row] == larr[64 + col]);
                bool selfp = ((row0 + row) == (col0 + col));
                bool edge = false;
                if (same && !selfp) {
                    double s = (double)acc[i][j][r];
                    if (s <= thrd - BAND) {
                        edge = true;
                    } else if (s <= thrd + BAND) {
                        // provisional decision; exact resolution deferred
                        edge = (s <= thrd);
                        int enc = ((row0 + row) << 12) | (col0 + col) |
                                  (diag ? 0 : (1 << 24)) |
                                  (edge ? (1 << 25) : 0);
                        int slot = atomicAdd(&rcn, 1);   // LDS atomic (fast)
                        if (slot < RCB) rcbuf[slot] = enc;
                    }
                }
                flags[row * 68 + col] = edge ? 1 : 0;
            }
        }
    __syncthreads();
    if (tid == 0) {                            // ONE global atomic per block
        int n = rcn < RCB ? rcn : RCB;
        rcbase = n ? atomicAdd(rc_cnt, n) : 0;
    }

    // ---- write bits/lm rows for (by,bx) region + row degrees ----
    {
        int r = tid >> 2, q = tid & 3;
        int cnti = 0;
        unsigned int bits16 = 0;
#pragma unroll
        for (int s = 0; s < 4; ++s) {
            int cb = q * 16 + s * 4;
            float4 f;
#pragma unroll
            for (int k2 = 0; k2 < 4; ++k2) {
                int c = cb + k2;
                bool fl = flags[r * 68 + c] != 0;
                cnti += fl ? 1 : 0;
                if (fl || (diag && r == c)) bits16 |= 1u << (s * 4 + k2);
                ((float*)&f)[k2] = (fl && (row0 + r < col0 + c)) ? 1.0f : 0.0f;
            }
            *(float4*)&lm[(size_t)(row0 + r) * NN + col0 + cb] = f;
        }
        unsigned int s1 = __shfl_down(bits16, 1);
        unsigned int s2 = __shfl_down(bits16, 2);
        unsigned int s3 = __shfl_down(bits16, 3);
        cnti += __shfl_down(cnti, 1);
        cnti += __shfl_down(cnti, 2);
        if (q == 0) {
            u64 u = (u64)bits16 | ((u64)s1 << 16) | ((u64)s2 << 32) |
                    ((u64)s3 << 48);
            abbits[(size_t)(row0 + r) * 64 + bx] = u;
            if (cnti) atomicAdd(&deg[row0 + r], cnti);
        }
    }

    // ---- mirror region (bx,by) for off-diagonal blocks ----
    if (!diag) {
        int c = tid >> 2, q = tid & 3;
        int cnti = 0;
        unsigned int bits16 = 0;
        float4 fz = {0.0f, 0.0f, 0.0f, 0.0f};
#pragma unroll
        for (int s = 0; s < 4; ++s) {
            int rb = q * 16 + s * 4;
#pragma unroll
            for (int k2 = 0; k2 < 4; ++k2) {
                bool fl = flags[(rb + k2) * 68 + c] != 0;
                cnti += fl ? 1 : 0;
                if (fl) bits16 |= 1u << (s * 4 + k2);
            }
            *(float4*)&lm[(size_t)(col0 + c) * NN + row0 + rb] = fz;
        }
        unsigned int s1 = __shfl_down(bits16, 1);
        unsigned int s2 = __shfl_down(bits16, 2);
        unsigned int s3 = __shfl_down(bits16, 3);
        cnti += __shfl_down(cnti, 1);
        cnti += __shfl_down(cnti, 2);
        if (q == 0) {
            u64 u = (u64)bits16 | ((u64)s1 << 16) | ((u64)s2 << 32) |
                    ((u64)s3 << 48);
            abbits[(size_t)(col0 + c) * 64 + by] = u;
            if (cnti) atomicAdd(&deg[col0 + c], cnti);
        }
    }

    // ---- flush rc buffer (coalesced; rcbase from block leader) ----
    __syncthreads();
    {
        int n = rcn < RCB ? rcn : RCB;
        if (tid < n) {
            int idx = rcbase + tid;
            if (idx < RC_CAP) rc_list[idx] = rcbuf[tid];
        }
    }
}

// ---------------------------------------------------------------------------
// rc_fix: exact fp64 resolution of band entries. One WAVE per entry; flips
// adjacency BITS via atomicOr/atomicAnd.
// ---------------------------------------------------------------------------
__global__ __launch_bounds__(256) void rc_fix(
    const float* __restrict__ x, const double* __restrict__ scal,
    const int* __restrict__ rc_cnt, const int* __restrict__ rc_list,
    u64* __restrict__ abbits, float* __restrict__ lm, int* __restrict__ deg) {
    int cnt = *rc_cnt;
    if (cnt > RC_CAP) cnt = RC_CAP;
    double thrd;
    {
        double c = scal[1];
        thrd = (c > 0.0) ? (scal[0] / c) : 0.0;
    }
    int lane = threadIdx.x & 63;
    int wid = (blockIdx.x * 256 + threadIdx.x) >> 6;
    int nw = (gridDim.x * 256) >> 6;
    for (int e = wid; e < cnt; e += nw) {
        int enc = rc_list[e];
        int c = enc & 0xFFF;
        int r = (enc >> 12) & 0xFFF;
        bool mirror = (enc >> 24) & 1;
        bool prov = (enc >> 25) & 1;
        const float* xi = x + (size_t)r * CD;
        const float* xj = x + (size_t)c * CD;
        double d = 0.0;
#pragma unroll
        for (int s = 0; s < 12; ++s)
            d += (double)xi[lane + s * 64] * (double)xj[lane + s * 64];
        for (int off = 32; off; off >>= 1) d += __shfl_down(d, off);
        if (lane == 0) {
            bool exact = (d <= thrd);
            if (exact != prov) {
                u64 mk = 1ull << (c & 63);
                if (exact) atomicOr(&abbits[(size_t)r * 64 + (c >> 6)], mk);
                else       atomicAnd(&abbits[(size_t)r * 64 + (c >> 6)], ~mk);
                lm[(size_t)r * NN + c] = (exact && r < c) ? 1.0f : 0.0f;
                int dlt = exact ? 1 : -1;
                atomicAdd(&deg[r], dlt);
                if (mirror) {
                    u64 mk2 = 1ull << (r & 63);
                    if (exact) atomicOr(&abbits[(size_t)c * 64 + (r >> 6)], mk2);
                    else       atomicAnd(&abbits[(size_t)c * 64 + (r >> 6)], ~mk2);
                    atomicAdd(&deg[c], dlt);
                }
            }
        }
    }
}

// ---------------------------------------------------------------------------
// PREP (fused): x -> f_g cols / x-out / xh(bf16)+xf(f16); W1,W2 transposes;
// per-label group sums as extra blocks.
// ---------------------------------------------------------------------------
__global__ __launch_bounds__(256) void prep_kernel(
    const float* __restrict__ x, const float* __restrict__ W1,
    const float* __restrict__ W2, const int* __restrict__ labels,
    float* __restrict__ fg, float* __restrict__ xo,
    ushortT* __restrict__ xh, ushortT* __restrict__ xf, ushortT* __restrict__ w1t,
    ushortT* __restrict__ w2t, double* __restrict__ gsum) {
    int b = blockIdx.x;
    if (b < 4096) {
        int t = threadIdx.x;
        if (t < 192) {
            float4 v = *(const float4*)&x[(size_t)b * CD + t * 4];
            *(float4*)&xo[(size_t)b * CD + t * 4] = v;
            fg[(size_t)b * FGD + t * 4 + 0] = v.x;
            fg[(size_t)b * FGD + t * 4 + 1] = v.y;
            fg[(size_t)b * FGD + t * 4 + 2] = v.z;
            fg[(size_t)b * FGD + t * 4 + 3] = v.w;
            us4 hh, ff;
            float* vp = (float*)&v;
#pragma unroll
            for (int k = 0; k < 4; ++k) {
                ((ushortT*)&hh)[k] = f2bf(vp[k]);
                _Float16 g = (_Float16)vp[k];
                ((ushortT*)&ff)[k] = *(ushortT*)&g;
            }
            *(us4*)&xh[(size_t)b * CD + t * 4] = hh;
            *(us4*)&xf[(size_t)b * CD + t * 4] = ff;
        }
        return;
    }
    if (b >= 4512) {
        // ---- gsum branch: per-label fp64 column sums (16 rows/block) ----
        int bb = b - 4512;
        int t = threadIdx.x;
        double a0[3] = {0, 0, 0}, a1[3] = {0, 0, 0};
        for (int rr = 0; rr < 16; ++rr) {
            int row = bb * 16 + rr;
            int lab = labels[row];
#pragma unroll
            for (int s = 0; s < 3; ++s) {
                double v = (double)x[(size_t)row * CD + t + s * 256];
                if (lab == 0) a0[s] += v; else a1[s] += v;
            }
        }
#pragma unroll
        for (int s = 0; s < 3; ++s) {
            atomicAdd(&gsum[t + s * 256], a0[s]);
            atomicAdd(&gsum[768 + t + s * 256], a1[s]);
        }
        return;
    }
    __shared__ float tT[32][33];
    const float* P;
    ushortT* T;
    int K, N, Npad, k0, n0;
    if (b < 4480) {
        int bb = b - 4096;
        P = W1; T = w1t; K = CD; N = HD; Npad = HD;
        k0 = (bb % 24) * 32; n0 = (bb / 24) * 32;
    } else {
        int bb = b - 4480;
        P = W2; T = w2t; K = HD; N = OD; Npad = 64;
        k0 = (bb % 16) * 32; n0 = (bb / 16) * 32;
    }
    int tx = threadIdx.x & 31, ty = threadIdx.x >> 5;
#pragma unroll
    for (int s = 0; s < 4; ++s) {
        int k = k0 + ty + s * 8, n = n0 + tx;
        tT[ty + s * 8][tx] = (k < K && n < N) ? P[(size_t)k * N + n] : 0.0f;
    }
    __syncthreads();
#pragma unroll
    for (int s = 0; s < 4; ++s) {
        int n = n0 + ty + s * 8, k = k0 + tx;
        if (n < Npad && k < K) T[(size_t)n * K + k] = f2bf(tT[tx][ty + s * 8]);
    }
}

// ---------------------------------------------------------------------------
// Split-K partial GEMM (N=64, bf16 A): P[kb][row][64]; grid (KS, M/64). (K6)
// ---------------------------------------------------------------------------
__global__ __launch_bounds__(256) void gemm_part(
    const ushortT* __restrict__ A, const ushortT* __restrict__ B,
    float* __restrict__ P, int M, int K, int KC) {
    __shared__ ushortT lds[2 * 64 * 72];
    int tid = threadIdx.x;
    int lane = tid & 63;
    int w = tid >> 6;
    int wr = w >> 1, wc = w & 1;
    int m = lane & 15, quad = lane >> 4;
    int kb = blockIdx.x;
    int row0 = blockIdx.y * 64;
    int kbase = kb * KC;

    f32x4 acc[2][2] = {{{0.f, 0.f, 0.f, 0.f}, {0.f, 0.f, 0.f, 0.f}},
                       {{0.f, 0.f, 0.f, 0.f}, {0.f, 0.f, 0.f, 0.f}}};

    for (int k0 = 0; k0 < KC; k0 += 64) {
#pragma unroll
        for (int t = 0; t < 2; ++t) {
            int id2 = tid + t * 256;
            int row = id2 >> 3, c8 = (id2 & 7) * 8;
            *(short8*)&lds[row * 72 + c8] =
                *(const short8*)&A[(size_t)(row0 + row) * K + kbase + k0 + c8];
            *(short8*)&lds[4608 + row * 72 + c8] =
                *(const short8*)&B[(size_t)row * K + kbase + k0 + c8];
        }
        __syncthreads();
#pragma unroll
        for (int ks = 0; ks < 2; ++ks) {
            short8 af[2], bf[2];
#pragma unroll
            for (int i = 0; i < 2; ++i)
                af[i] = *(const short8*)&lds[(wr * 32 + i * 16 + m) * 72 +
                                             ks * 32 + quad * 8];
#pragma unroll
            for (int j = 0; j < 2; ++j)
                bf[j] = *(const short8*)&lds[4608 + (wc * 32 + j * 16 + m) * 72 +
                                             ks * 32 + quad * 8];
#pragma unroll
            for (int i = 0; i < 2; ++i)
#pragma unroll
                for (int j = 0; j < 2; ++j)
                    acc[i][j] = __builtin_amdgcn_mfma_f32_16x16x32_bf16(
                        af[i], bf[j], acc[i][j], 0, 0, 0);
        }
        __syncthreads();
    }
#pragma unroll
    for (int i = 0; i < 2; ++i)
#pragma unroll
        for (int j = 0; j < 2; ++j)
#pragma unroll
            for (int r = 0; r < 4; ++r) {
                int row = wr * 32 + i * 16 + quad * 4 + r;
                int col = wc * 32 + j * 16 + m;
                P[((size_t)kb * M + row0 + row) * 64 + col] = acc[i][j][r];
            }
}

// ---------------------------------------------------------------------------
// Split-K partial GEMM (N=64, BIT A): A tile expanded from packed adjacency
// bits in LDS — no bf16 A in HBM. (K7)
// ---------------------------------------------------------------------------
__global__ __launch_bounds__(256) void gemm_partB(
    const u64* __restrict__ Abits, const ushortT* __restrict__ B,
    float* __restrict__ P, int M, int K, int KC) {
    __shared__ ushortT lds[2 * 64 * 72];
    int tid = threadIdx.x;
    int lane = tid & 63;
    int w = tid >> 6;
    int wr = w >> 1, wc = w & 1;
    int m = lane & 15, quad = lane >> 4;
    int kb = blockIdx.x;
    int row0 = blockIdx.y * 64;
    int kbase = kb * KC;
    int er = tid >> 2, eq = tid & 3;

    f32x4 acc[2][2] = {{{0.f, 0.f, 0.f, 0.f}, {0.f, 0.f, 0.f, 0.f}},
                       {{0.f, 0.f, 0.f, 0.f}, {0.f, 0.f, 0.f, 0.f}}};

    for (int k0 = 0; k0 < KC; k0 += 64) {
#pragma unroll
        for (int t = 0; t < 2; ++t) {
            int id2 = tid + t * 256;
            int row = id2 >> 3, c8 = (id2 & 7) * 8;
            *(short8*)&lds[4608 + row * 72 + c8] =
                *(const short8*)&B[(size_t)row * K + kbase + k0 + c8];
        }
        {
            u64 bits = Abits[(size_t)(row0 + er) * 64 + ((kbase + k0) >> 6)];
            unsigned int half = (unsigned int)(bits >> (eq * 16)) & 0xFFFFu;
            short8 v0, v1;
#pragma unroll
            for (int k = 0; k < 8; ++k) {
                ((ushortT*)&v0)[k] =
                    ((half >> k) & 1) ? (ushortT)0x3F80 : (ushortT)0;
                ((ushortT*)&v1)[k] =
                    ((half >> (k + 8)) & 1) ? (ushortT)0x3F80 : (ushortT)0;
            }
            *(short8*)&lds[er * 72 + eq * 16] = v0;
            *(short8*)&lds[er * 72 + eq * 16 + 8] = v1;
        }
        __syncthreads();
#pragma unroll
        for (int ks = 0; ks < 2; ++ks) {
            short8 af[2], bf[2];
#pragma unroll
            for (int i = 0; i < 2; ++i)
                af[i] = *(const short8*)&lds[(wr * 32 + i * 16 + m) * 72 +
                                             ks * 32 + quad * 8];
#pragma unroll
            for (int j = 0; j < 2; ++j)
                bf[j] = *(const short8*)&lds[4608 + (wc * 32 + j * 16 + m) * 72 +
                                             ks * 32 + quad * 8];
#pragma unroll
            for (int i = 0; i < 2; ++i)
#pragma unroll
                for (int j = 0; j < 2; ++j)
                    acc[i][j] = __builtin_amdgcn_mfma_f32_16x16x32_bf16(
                        af[i], bf[j], acc[i][j], 0, 0, 0);
        }
        __syncthreads();
    }
#pragma unroll
    for (int i = 0; i < 2; ++i)
#pragma unroll
        for (int j = 0; j < 2; ++j)
#pragma unroll
            for (int r = 0; r < 4; ++r) {
                int row = wr * 32 + i * 16 + quad * 4 + r;
                int col = wc * 32 + j * 16 + m;
                P[((size_t)kb * M + row0 + row) * 64 + col] = acc[i][j][r];
            }
}

// ---------------------------------------------------------------------------
// Split-K WIDE partial GEMM (BIT A, BF16 B with fused dinv scaling), R13:
// M-tile 128 (R12-proven) + bf16 B operand (halves B stream 268->134 MB).
// grid (HD/64, NN/128, 4). Per wave 32x64 via acc[2][4].
// ---------------------------------------------------------------------------
__global__ __launch_bounds__(256) void gemm_partWB(
    const u64* __restrict__ Abits, const ushortT* __restrict__ Bb,
    const int* __restrict__ deg, float* __restrict__ P,
    int M, int K, int KC, int ldP) {
    __shared__ ushortT lds[192 * 72];           // A:[0,128*72) B:[128*72,...)
    __shared__ float dinvK[1024];               // KC <= 1024
    const int BO = 128 * 72;
    int tid = threadIdx.x;
    int lane = tid & 63;
    int w = tid >> 6;                           // wave 0..3 -> rows w*32..+32
    int m = lane & 15, quad = lane >> 4;
    int col0 = blockIdx.x * 64;
    int row0 = blockIdx.y * 128;
    int kb = blockIdx.z;
    int kbase = kb * KC;
    int er = tid >> 1, eq = tid & 1;            // 128 rows x 2 half-u64s

    for (int v = tid; v < KC; v += 256)
        dinvK[v] = 1.0f / sqrtf((float)(1 + deg[kbase + v]));
    __syncthreads();

    f32x4 acc[2][4];
#pragma unroll
    for (int i = 0; i < 2; ++i)
#pragma unroll
        for (int j = 0; j < 4; ++j) acc[i][j] = {0.f, 0.f, 0.f, 0.f};

    for (int k0 = 0; k0 < KC; k0 += 64) {
        // B stage: 64 cols x 64 K, bf16 -> f32 x dinv -> bf16
#pragma unroll
        for (int t = 0; t < 2; ++t) {
            int id2 = tid + t * 256;
            int row = id2 >> 3, c8 = (id2 & 7) * 8;
            short8 v = *(const short8*)&Bb[(size_t)(col0 + row) * K +
                                           kbase + k0 + c8];
            short8 o;
#pragma unroll
            for (int k = 0; k < 8; ++k)
                ((ushortT*)&o)[k] = f2bf(bf2f(((const ushortT*)&v)[k]) *
                                         dinvK[k0 + c8 + k]);
            *(short8*)&lds[BO + row * 72 + c8] = o;
        }
        // A stage: 128 rows of packed bits; each thread expands 32 bits
        {
            u64 bits = Abits[(size_t)(row0 + er) * 64 + ((kbase + k0) >> 6)];
            unsigned int hf = (unsigned int)(bits >> (eq * 32));
            short8 v0, v1, v2, v3;
#pragma unroll
            for (int k = 0; k < 8; ++k) {
                ((ushortT*)&v0)[k] = ((hf >> k) & 1) ? (ushortT)0x3F80 : (ushortT)0;
                ((ushortT*)&v1)[k] = ((hf >> (k + 8)) & 1) ? (ushortT)0x3F80 : (ushortT)0;
                ((ushortT*)&v2)[k] = ((hf >> (k + 16)) & 1) ? (ushortT)0x3F80 : (ushortT)0;
                ((ushortT*)&v3)[k] = ((hf >> (k + 24)) & 1) ? (ushortT)0x3F80 : (ushortT)0;
            }
            int ab = er * 72 + eq * 32;
            *(short8*)&lds[ab + 0] = v0;
            *(short8*)&lds[ab + 8] = v1;
            *(short8*)&lds[ab + 16] = v2;
            *(short8*)&lds[ab + 24] = v3;
        }
        __syncthreads();
#pragma unroll
        for (int ks = 0; ks < 2; ++ks) {
            short8 af[2], bf[4];
#pragma unroll
            for (int i = 0; i < 2; ++i)
                af[i] = *(const short8*)&lds[(w * 32 + i * 16 + m) * 72 +
                                             ks * 32 + quad * 8];
#pragma unroll
            for (int j = 0; j < 4; ++j)
                bf[j] = *(const short8*)&lds[BO + (j * 16 + m) * 72 +
                                             ks * 32 + quad * 8];
#pragma unroll
            for (int i = 0; i < 2; ++i)
#pragma unroll
                for (int j = 0; j < 4; ++j)
                    acc[i][j] = __builtin_amdgcn_mfma_f32_16x16x32_bf16(
                        af[i], bf[j], acc[i][j], 0, 0, 0);
        }
        __syncthreads();
    }
#pragma unroll
    for (int i = 0; i < 2; ++i)
#pragma unroll
        for (int j = 0; j < 4; ++j)
#pragma unroll
            for (int r = 0; r < 4; ++r) {
                int row = row0 + w * 32 + i * 16 + quad * 4 + r;
                int col = col0 + j * 16 + m;
                P[((size_t)kb * M + row) * ldP + col] = acc[i][j][r];
            }
}

// ---------------------------------------------------------------------------
// k5 epilogue: hb[r][c] = bf16(relu(dinv[r]*sum_kb P5[kb][r][c] + b1[c])).
// SK=4.
// ---------------------------------------------------------------------------
__global__ __launch_bounds__(256) void k5_epi(const float* __restrict__ P5,
                                              const int* __restrict__ deg,
                                              const float* __restrict__ b1,
                                              ushortT* __restrict__ hb) {
    int tid = threadIdx.x;
    int cg = tid & 127;      // 128 groups of float4 = 512 cols
    int rr = tid >> 7;       // 0..1
#pragma unroll
    for (int p = 0; p < 2; ++p) {
        int r = blockIdx.x * 4 + p * 2 + rr;
        float dv = dinv_of(deg[r]);
        float4 s = {0.f, 0.f, 0.f, 0.f};
#pragma unroll
        for (int kb = 0; kb < 4; ++kb) {
            float4 v = *(const float4*)&P5[((size_t)kb * NN + r) * HD + cg * 4];
            s.x += v.x; s.y += v.y; s.z += v.z; s.w += v.w;
        }
        float4 bv = *(const float4*)&b1[cg * 4];
        us4 o;
        o[0] = f2bf(fmaxf(s.x * dv + bv.x, 0.f));
        o[1] = f2bf(fmaxf(s.y * dv + bv.y, 0.f));
        o[2] = f2bf(fmaxf(s.z * dv + bv.z, 0.f));
        o[3] = f2bf(fmaxf(s.w * dv + bv.w, 0.f));
        *(us4*)&hb[(size_t)r * HD + cg * 4] = o;
    }
}

// ---------------------------------------------------------------------------
// k6 epilogue: hw2sT[c][r] = bf16(dinv[r] * sum_kb P6[kb][r][c]); 64 blocks.
// ---------------------------------------------------------------------------
__global__ __launch_bounds__(256) void k6_epi(const float* __restrict__ P6,
                                              const int* __restrict__ deg,
                                              ushortT* __restrict__ hw2sT) {
    __shared__ ushortT Th[64 * 72];
    int row0 = blockIdx.x * 64;
    int tid = threadIdx.x;
    int rl = tid >> 2, q = tid & 3;
    float dv = dinv_of(deg[row0 + rl]);
#pragma unroll
    for (int s = 0; s < 16; ++s) {
        int c = q * 16 + s;
        float v = 0.f;
#pragma unroll
        for (int kb = 0; kb < 8; ++kb)
            v += P6[((size_t)kb * NN + row0 + rl) * 64 + c];
        Th[c * 72 + rl] = f2bf(v * dv);
    }
    __syncthreads();
#pragma unroll
    for (int t = 0; t < 2; ++t) {
        int id2 = tid + t * 256;
        int cc = id2 >> 3, chunk = id2 & 7;
        *(short8*)&hw2sT[(size_t)cc * NN + row0 + chunk * 8] =
            *(const short8*)&Th[cc * 72 + chunk * 8];
    }
}

// ---------------------------------------------------------------------------
// k7 epilogue + final fc: writes g into f_g AND computes out[r].
// ---------------------------------------------------------------------------
__global__ __launch_bounds__(256) void k7_epi_out(
    const float* __restrict__ P7, const int* __restrict__ deg,
    const float* __restrict__ b2, const float* __restrict__ fcW,
    const float* __restrict__ fcb, float* __restrict__ fg,
    float* __restrict__ out) {
    int row0 = blockIdx.x * 64;
    int tid = threadIdx.x;
    int rl = tid >> 2, q = tid & 3;
    int r = row0 + rl;
    float dv = dinv_of(deg[r]);
    float sg = 0.f;
#pragma unroll
    for (int s = 0; s < 16; ++s) {
        int c = q * 16 + s;
        if (c < OD) {
            float v = 0.f;
#pragma unroll
            for (int kb = 0; kb < 16; ++kb)
                v += P7[((size_t)kb * NN + r) * 64 + c];
            v = v * dv + b2[c];
            fg[(size_t)r * FGD + CD + c] = v;
            sg += v * fcW[CD + c];
        }
    }
    // x-part dot (f_g rows are 8B-aligned: use float2)
    const float* fr = fg + (size_t)r * FGD;
    float sx = 0.f;
    for (int k = q * 192; k < (q + 1) * 192; k += 2) {
        float2 vv = *(const float2*)&fr[k];
        float2 ww = *(const float2*)&fcW[k];
        sx += vv.x * ww.x + vv.y * ww.y;
    }
    float s = sx + sg;
    s += __shfl_down(s, 1);
    s += __shfl_down(s, 2);
    if (q == 0) out[r] = s + fcb[0];
}

extern "C" void kernel_launch(void* const* d_in, const int* in_sizes, int n_in,
                              void* d_out, int out_size, void* d_ws, size_t ws_size,
                              hipStream_t stream) {
    const float* x = (const float*)d_in[0];
    const int* labels = (const int*)d_in[1];
    const float* W1 = (const float*)d_in[2];
    const float* b1 = (const float*)d_in[3];
    const float* W2 = (const float*)d_in[4];
    const float* b2 = (const float*)d_in[5];
    const float* fcW = (const float*)d_in[6];
    const float* fcb = (const float*)d_in[7];
    float* outp = (float*)d_out;

    const size_t o_out = 0;
    const size_t o_fg = 4096;
    const size_t o_lm = o_fg + (size_t)NN * FGD;
    const size_t o_x = o_lm + (size_t)NN * NN;

    // workspace layout
    char* ws = (char*)d_ws;
    size_t off = 0;
    u64* abbits = (u64*)(ws + off); off += (size_t)NN * 64 * 8;          // 2 MiB
    ushortT* xh = (ushortT*)(ws + off); off += (size_t)NN * CD * 2;
    ushortT* xf = (ushortT*)(ws + off); off += (size_t)NN * CD * 2;      // f16
    ushortT* w1t = (ushortT*)(ws + off); off += (size_t)HD * CD * 2;
    ushortT* xw1b = (ushortT*)(ws + off); off += (size_t)HD * NN * 2;    // 4 MiB
    ushortT* hb = (ushortT*)(ws + off); off += (size_t)NN * HD * 2;      // 4 MiB
    ushortT* w2t = (ushortT*)(ws + off); off += (size_t)64 * HD * 2;
    ushortT* hw2sT = (ushortT*)(ws + off); off += (size_t)64 * NN * 2;
    char* zbase = ws + off;
    int* deg = (int*)(ws + off); off += (size_t)NN * 4;
    double* gsum = (double*)(ws + off); off += 1536 * 8;
    double* scal = (double*)(ws + off); off += 16;
    int* rc_cnt = (int*)(ws + off); off += 16;
    size_t zbytes = (size_t)NN * 4 + 1536 * 8 + 16 + 16;
    // UNION region: rc_list (1 MiB) -> P5 (32 MiB, SK=4) -> P6 (8 MiB) ->
    // P7 (16 MiB); strictly sequential lifetimes. xw1b OUTSIDE the union.
    char* uni = ws + off;
    int* rc_list = (int*)uni;                       // 1 MiB
    float* P5 = (float*)uni;                        // 32 MiB (4*NN*HD*4)
    float* P6 = (float*)uni;                        // 8 MiB  (8*NN*64*4)
    float* P7 = (float*)uni;                        // 16 MiB (16*NN*64*4)
    off += (size_t)4 * NN * HD * 4;

    hipMemsetAsync(zbase, 0, zbytes, stream);

    // prep (x casts + weight transposes) FUSED with gsum (4768 blocks)
    prep_kernel<<<4768, 256, 0, stream>>>(x, W1, W2, labels, outp + o_fg,
                                          outp + o_x, xh, xf, w1t, w2t, gsum);

    // threshold scalars
    gdot_kernel<<<1, 256, 0, stream>>>(gsum, labels, scal);

    // sim (f16, packed bits, deferred band) FUSED with K4 (bf16 x@W1^T)
    simk4<<<2592, 256, 0, stream>>>(xf, xh, w1t, labels, scal, abbits,
                                    outp + o_lm, deg, rc_cnt, rc_list, xw1b);

    // exact fp64 resolution of band entries (one wave per entry)
    rc_fix<<<512, 256, 0, stream>>>(x, scal, rc_cnt, rc_list, abbits, outp + o_lm,
                                    deg);

    // K5: split-K (SK=4), M-tile 128, bit-A + bf16-B with fused dinv scaling
    gemm_partWB<<<dim3(HD / 64, NN / 128, 4), 256, 0, stream>>>(
        abbits, xw1b, deg, P5, NN, NN, NN / 4, HD);
    k5_epi<<<NN / 4, 256, 0, stream>>>(P5, deg, b1, hb);

    // K6: hw2sT via split-K (SK=8) partials + epilogue
    gemm_part<<<dim3(8, NN / 64), 256, 0, stream>>>(hb, w2t, P6, NN, HD, HD / 8);
    k6_epi<<<NN / 64, 256, 0, stream>>>(P6, deg, hw2sT);

    // K7: g via split-K (SK=16) partials (bit-A) + fused epilogue/out
    gemm_partB<<<dim3(16, NN / 64), 256, 0, stream>>>(abbits, hw2sT, P7, NN, NN,
                                                      NN / 16);
    k7_epi_out<<<NN / 64, 256, 0, stream>>>(P7, deg, b2, fcW, fcb, outp + o_fg,
                                            outp + o_out);
}

// Round 15
// 296.531 us; speedup vs baseline: 1.0042x; 1.0042x over previous
//
#include <hip/hip_runtime.h>
#include <hip/hip_bf16.h>
#include <math.h>

#define NN 4096
#define CD 768
#define HD 512
#define OD 50
#define FGD 818   // CD + OD

typedef short short8 __attribute__((ext_vector_type(8)));
typedef _Float16 half8 __attribute__((ext_vector_type(8)));
typedef float f32x4 __attribute__((ext_vector_type(4)));
typedef unsigned short us4 __attribute__((ext_vector_type(4)));
typedef unsigned short ushortT;
typedef unsigned char uchar;
typedef unsigned long long u64;

__device__ inline ushortT f2bf(float v) {
    __hip_bfloat16 b = __float2bfloat16(v);
    return *(ushortT*)&b;
}
__device__ inline float bf2f(ushortT u) {
    __hip_bfloat16 b = *(__hip_bfloat16*)&u;
    return __bfloat162float(b);
}
__device__ inline float dinv_of(int d) {
    return (float)(1.0 / sqrt((double)(1 + d)));
}

// ---------------------------------------------------------------------------
// K0b: threshold scalars. scal[0] = 2*S0.S1, scal[1] = 2*n0*n1.
// ---------------------------------------------------------------------------
__global__ __launch_bounds__(256) void gdot_kernel(const double* __restrict__ gsum,
                                                   const int* __restrict__ labels,
                                                   double* __restrict__ scal) {
    int t = threadIdx.x;
    double d = 0.0;
    for (int c = t; c < CD; c += 256) d += gsum[c] * gsum[768 + c];
    int n0 = 0;
    for (int i = t; i < NN; i += 256) n0 += (labels[i] == 0) ? 1 : 0;
    for (int off = 32; off; off >>= 1) {
        d += __shfl_down(d, off);
        n0 += __shfl_down(n0, off);
    }
    __shared__ double sd[4];
    __shared__ int sn[4];
    int wid = t >> 6, lane = t & 63;
    if (lane == 0) { sd[wid] = d; sn[wid] = n0; }
    __syncthreads();
    if (t == 0) {
        double D = sd[0] + sd[1] + sd[2] + sd[3];
        double N0 = (double)(sn[0] + sn[1] + sn[2] + sn[3]);
        scal[0] = 2.0 * D;
        scal[1] = 2.0 * N0 * ((double)NN - N0);
    }
}

// ---------------------------------------------------------------------------
// SIMK4 (R14): sim staging keeps R6/R8 structure (reg-prefetch + ds_write,
// single-buffered) but the sim LDS layout is now 64-stride with XOR chunk
// swizzle (chunk j of row r at j ^ (r&7)) on BOTH ds_write and ds_read —
// kills the 4.3M bank-conflict cycles without R7's occupancy loss.
// K4 branch (blocks 2080..2591, f32 x@W1^T out) unchanged (72-stride).
// ---------------------------------------------------------------------------
#define BAND 0.10
#define RC_CAP (1 << 18)
#define RCB 256

__global__ __launch_bounds__(256) void simk4(
    const ushortT* __restrict__ xf, const ushortT* __restrict__ xh,
    const ushortT* __restrict__ w1t, const int* __restrict__ labels,
    const double* __restrict__ scal, u64* __restrict__ abbits,
    float* __restrict__ lm, int* __restrict__ deg,
    int* __restrict__ rc_cnt, int* __restrict__ rc_list,
    float* __restrict__ xw1f) {
    __shared__ ushortT lds[2 * 64 * 72];    // 18432 B staging / flags
    __shared__ int larr[128];
    __shared__ int rcbuf[RCB];
    __shared__ int rcn, rcbase;
    int tid = threadIdx.x;
    int lane = tid & 63;
    int w = tid >> 6;
    int wr = w >> 1, wc = w & 1;
    int m = lane & 15, quad = lane >> 4;

    if (blockIdx.x >= 2080) {
        // ---------------- K4 branch: xw1f^T = (x @ W1)^T, f32 ----------------
        int idx = blockIdx.x - 2080;
        int row0 = (idx >> 3) * 64, col0 = (idx & 7) * 64;
        f32x4 acc[2][2] = {{{0.f, 0.f, 0.f, 0.f}, {0.f, 0.f, 0.f, 0.f}},
                           {{0.f, 0.f, 0.f, 0.f}, {0.f, 0.f, 0.f, 0.f}}};
        for (int k0 = 0; k0 < CD; k0 += 64) {
#pragma unroll
            for (int t = 0; t < 2; ++t) {
                int id2 = tid + t * 256;
                int row = id2 >> 3, c8 = (id2 & 7) * 8;
                *(short8*)&lds[row * 72 + c8] =
                    *(const short8*)&xh[(size_t)(row0 + row) * CD + k0 + c8];
                *(short8*)&lds[4608 + row * 72 + c8] =
                    *(const short8*)&w1t[(size_t)(col0 + row) * CD + k0 + c8];
            }
            __syncthreads();
#pragma unroll
            for (int ks = 0; ks < 2; ++ks) {
                short8 af[2], bf[2];
#pragma unroll
                for (int i = 0; i < 2; ++i)
                    af[i] = *(const short8*)&lds[(wr * 32 + i * 16 + m) * 72 +
                                                 ks * 32 + quad * 8];
#pragma unroll
                for (int j = 0; j < 2; ++j)
                    bf[j] = *(const short8*)&lds[4608 +
                                                 (wc * 32 + j * 16 + m) * 72 +
                                                 ks * 32 + quad * 8];
#pragma unroll
                for (int i = 0; i < 2; ++i)
#pragma unroll
                    for (int j = 0; j < 2; ++j)
                        acc[i][j] = __builtin_amdgcn_mfma_f32_16x16x32_bf16(
                            af[i], bf[j], acc[i][j], 0, 0, 0);
            }
            __syncthreads();
        }
#pragma unroll
        for (int i = 0; i < 2; ++i)
#pragma unroll
            for (int j = 0; j < 2; ++j) {
                int row = row0 + wr * 32 + i * 16 + quad * 4;
                int col = col0 + wc * 32 + j * 16 + m;
                *(f32x4*)&xw1f[(size_t)col * NN + row] = acc[i][j];
            }
        return;
    }

    // ------------------------- sim branch -------------------------
    // super-tile + XCD-chunked mapping (2080 = 8 XCD chunks x 260)
    int bid = blockIdx.x;
    int sid = (bid & 7) * 260 + (bid >> 3);   // bijective; xcd gets contig sids
    int sby = 0, rem = sid;
    for (; sby < 8; ++sby) {
        int rowsz = 36 + (7 - sby) * 64;      // diag ST (36) + off-diag STs (64)
        if (rem < rowsz) break;
        rem -= rowsz;
    }
    int sbx, iby, ibx;
    if (rem < 36) {                            // diagonal super-tile (8x8 tri)
        sbx = sby;
        iby = 0;
        while (rem >= 8 - iby) { rem -= 8 - iby; ++iby; }
        ibx = iby + rem;
    } else {                                   // off-diagonal super-tiles
        rem -= 36;
        sbx = sby + 1 + (rem >> 6);
        int u = rem & 63;
        iby = u >> 3; ibx = u & 7;
    }
    int by = sby * 8 + iby, bx = sbx * 8 + ibx;
    bool diag = (bx == by);
    int row0 = by * 64, col0 = bx * 64;

    if (tid == 0) rcn = 0;
    if (tid < 64) larr[tid] = labels[row0 + tid];
    else if (tid < 128) larr[tid] = labels[col0 + tid - 64];

    f32x4 acc[2][2] = {{{0.f, 0.f, 0.f, 0.f}, {0.f, 0.f, 0.f, 0.f}},
                       {{0.f, 0.f, 0.f, 0.f}, {0.f, 0.f, 0.f, 0.f}}};

    const size_t rowbase = (size_t)row0 * CD;
    const size_t colbase = (size_t)col0 * CD;
    short8 rg[2][2];
#pragma unroll
    for (int tt = 0; tt < 2; ++tt) {
        int id2 = tid + tt * 256;
        int row = id2 >> 3, c8 = (id2 & 7) * 8;
        rg[tt][0] = *(const short8*)&xf[rowbase + (size_t)row * CD + c8];
        rg[tt][1] = *(const short8*)&xf[colbase + (size_t)row * CD + c8];
    }

    for (int k0 = 0; k0 < CD; k0 += 64) {
        __syncthreads();                       // prev compute done; LDS free
#pragma unroll
        for (int tt = 0; tt < 2; ++tt) {
            int id2 = tid + tt * 256;
            int row = id2 >> 3, j = id2 & 7;
            int c8s = ((j ^ (row & 7)) << 3);  // XOR chunk swizzle
            *(short8*)&lds[row * 64 + c8s] = rg[tt][0];
            *(short8*)&lds[4096 + row * 64 + c8s] = rg[tt][1];
        }
        __syncthreads();
        if (k0 + 64 < CD) {                    // prefetch next K-step early
#pragma unroll
            for (int tt = 0; tt < 2; ++tt) {
                int id2 = tid + tt * 256;
                int row = id2 >> 3, c8 = (id2 & 7) * 8 + k0 + 64;
                rg[tt][0] = *(const short8*)&xf[rowbase + (size_t)row * CD + c8];
                rg[tt][1] = *(const short8*)&xf[colbase + (size_t)row * CD + c8];
            }
        }
#pragma unroll
        for (int ks = 0; ks < 2; ++ks) {
            half8 ah[2], bh[2];
            int jj = ks * 4 + quad;            // logical chunk 0..7
#pragma unroll
            for (int i = 0; i < 2; ++i) {
                int row = wr * 32 + i * 16 + m;
                ah[i] = *(const half8*)&lds[row * 64 +
                                            ((jj ^ (row & 7)) << 3)];
            }
#pragma unroll
            for (int j = 0; j < 2; ++j) {
                int row = wc * 32 + j * 16 + m;
                bh[j] = *(const half8*)&lds[4096 + row * 64 +
                                            ((jj ^ (row & 7)) << 3)];
            }
#pragma unroll
            for (int i = 0; i < 2; ++i)
#pragma unroll
                for (int j = 0; j < 2; ++j)
                    acc[i][j] = __builtin_amdgcn_mfma_f32_16x16x32_f16(
                        ah[i], bh[j], acc[i][j], 0, 0, 0);
        }
    }
    __syncthreads();                           // before flags alias LDS

    // ---- edge flags (alias staging LDS); band entries -> LDS buffer ----
    double thrd;
    {
        double cnt = scal[1];
        thrd = (cnt > 0.0) ? (scal[0] / cnt) : 0.0;
    }
    uchar* flags = (uchar*)lds;             // [64][68]
#pragma unroll
    for (int i = 0; i < 2; ++i)
#pragma unroll
        for (int j = 0; j < 2; ++j) {
#pragma unroll
            for (int r = 0; r < 4; ++r) {
                int row = wr * 32 + i * 16 + quad * 4 + r;
                int col = wc * 32 + j * 16 + m;
                bool same = (larr[row] == larr[64 + col]);
                bool selfp = ((row0 + row) == (col0 + col));
                bool edge = false;
                if (same && !selfp) {
                    double s = (double)acc[i][j][r];
                    if (s <= thrd - BAND) {
                        edge = true;
                    } else if (s <= thrd + BAND) {
                        // provisional decision; exact resolution deferred
                        edge = (s <= thrd);
                        int enc = ((row0 + row) << 12) | (col0 + col) |
                                  (diag ? 0 : (1 << 24)) |
                                  (edge ? (1 << 25) : 0);
                        int slot = atomicAdd(&rcn, 1);   // LDS atomic (fast)
                        if (slot < RCB) rcbuf[slot] = enc;
                    }
                }
                flags[row * 68 + col] = edge ? 1 : 0;
            }
        }
    __syncthreads();
    if (tid == 0) {                            // ONE global atomic per block
        int n = rcn < RCB ? rcn : RCB;
        rcbase = n ? atomicAdd(rc_cnt, n) : 0;
    }

    // ---- write bits/lm rows for (by,bx) region + row degrees ----
    {
        int r = tid >> 2, q = tid & 3;
        int cnti = 0;
        unsigned int bits16 = 0;
#pragma unroll
        for (int s = 0; s < 4; ++s) {
            int cb = q * 16 + s * 4;
            float4 f;
#pragma unroll
            for (int k2 = 0; k2 < 4; ++k2) {
                int c = cb + k2;
                bool fl = flags[r * 68 + c] != 0;
                cnti += fl ? 1 : 0;
                if (fl || (diag && r == c)) bits16 |= 1u << (s * 4 + k2);
                ((float*)&f)[k2] = (fl && (row0 + r < col0 + c)) ? 1.0f : 0.0f;
            }
            *(float4*)&lm[(size_t)(row0 + r) * NN + col0 + cb] = f;
        }
        unsigned int s1 = __shfl_down(bits16, 1);
        unsigned int s2 = __shfl_down(bits16, 2);
        unsigned int s3 = __shfl_down(bits16, 3);
        cnti += __shfl_down(cnti, 1);
        cnti += __shfl_down(cnti, 2);
        if (q == 0) {
            u64 u = (u64)bits16 | ((u64)s1 << 16) | ((u64)s2 << 32) |
                    ((u64)s3 << 48);
            abbits[(size_t)(row0 + r) * 64 + bx] = u;
            if (cnti) atomicAdd(&deg[row0 + r], cnti);
        }
    }

    // ---- mirror region (bx,by) for off-diagonal blocks ----
    if (!diag) {
        int c = tid >> 2, q = tid & 3;
        int cnti = 0;
        unsigned int bits16 = 0;
        float4 fz = {0.0f, 0.0f, 0.0f, 0.0f};
#pragma unroll
        for (int s = 0; s < 4; ++s) {
            int rb = q * 16 + s * 4;
#pragma unroll
            for (int k2 = 0; k2 < 4; ++k2) {
                bool fl = flags[(rb + k2) * 68 + c] != 0;
                cnti += fl ? 1 : 0;
                if (fl) bits16 |= 1u << (s * 4 + k2);
            }
            *(float4*)&lm[(size_t)(col0 + c) * NN + row0 + rb] = fz;
        }
        unsigned int s1 = __shfl_down(bits16, 1);
        unsigned int s2 = __shfl_down(bits16, 2);
        unsigned int s3 = __shfl_down(bits16, 3);
        cnti += __shfl_down(cnti, 1);
        cnti += __shfl_down(cnti, 2);
        if (q == 0) {
            u64 u = (u64)bits16 | ((u64)s1 << 16) | ((u64)s2 << 32) |
                    ((u64)s3 << 48);
            abbits[(size_t)(col0 + c) * 64 + by] = u;
            if (cnti) atomicAdd(&deg[col0 + c], cnti);
        }
    }

    // ---- flush rc buffer (coalesced; rcbase from block leader) ----
    __syncthreads();
    {
        int n = rcn < RCB ? rcn : RCB;
        if (tid < n) {
            int idx = rcbase + tid;
            if (idx < RC_CAP) rc_list[idx] = rcbuf[tid];
        }
    }
}

// ---------------------------------------------------------------------------
// rc_fix: exact fp64 resolution of band entries. One WAVE per entry; flips
// adjacency BITS via atomicOr/atomicAnd.
// ---------------------------------------------------------------------------
__global__ __launch_bounds__(256) void rc_fix(
    const float* __restrict__ x, const double* __restrict__ scal,
    const int* __restrict__ rc_cnt, const int* __restrict__ rc_list,
    u64* __restrict__ abbits, float* __restrict__ lm, int* __restrict__ deg) {
    int cnt = *rc_cnt;
    if (cnt > RC_CAP) cnt = RC_CAP;
    double thrd;
    {
        double c = scal[1];
        thrd = (c > 0.0) ? (scal[0] / c) : 0.0;
    }
    int lane = threadIdx.x & 63;
    int wid = (blockIdx.x * 256 + threadIdx.x) >> 6;
    int nw = (gridDim.x * 256) >> 6;
    for (int e = wid; e < cnt; e += nw) {
        int enc = rc_list[e];
        int c = enc & 0xFFF;
        int r = (enc >> 12) & 0xFFF;
        bool mirror = (enc >> 24) & 1;
        bool prov = (enc >> 25) & 1;
        const float* xi = x + (size_t)r * CD;
        const float* xj = x + (size_t)c * CD;
        double d = 0.0;
#pragma unroll
        for (int s = 0; s < 12; ++s)
            d += (double)xi[lane + s * 64] * (double)xj[lane + s * 64];
        for (int off = 32; off; off >>= 1) d += __shfl_down(d, off);
        if (lane == 0) {
            bool exact = (d <= thrd);
            if (exact != prov) {
                u64 mk = 1ull << (c & 63);
                if (exact) atomicOr(&abbits[(size_t)r * 64 + (c >> 6)], mk);
                else       atomicAnd(&abbits[(size_t)r * 64 + (c >> 6)], ~mk);
                lm[(size_t)r * NN + c] = (exact && r < c) ? 1.0f : 0.0f;
                int dlt = exact ? 1 : -1;
                atomicAdd(&deg[r], dlt);
                if (mirror) {
                    u64 mk2 = 1ull << (r & 63);
                    if (exact) atomicOr(&abbits[(size_t)c * 64 + (r >> 6)], mk2);
                    else       atomicAnd(&abbits[(size_t)c * 64 + (r >> 6)], ~mk2);
                    atomicAdd(&deg[c], dlt);
                }
            }
        }
    }
}

// ---------------------------------------------------------------------------
// PREP (fused): x -> f_g cols / x-out / xh(bf16)+xf(f16); W1,W2 transposes;
// per-label group sums as extra blocks.
// ---------------------------------------------------------------------------
__global__ __launch_bounds__(256) void prep_kernel(
    const float* __restrict__ x, const float* __restrict__ W1,
    const float* __restrict__ W2, const int* __restrict__ labels,
    float* __restrict__ fg, float* __restrict__ xo,
    ushortT* __restrict__ xh, ushortT* __restrict__ xf, ushortT* __restrict__ w1t,
    ushortT* __restrict__ w2t, double* __restrict__ gsum) {
    int b = blockIdx.x;
    if (b < 4096) {
        int t = threadIdx.x;
        if (t < 192) {
            float4 v = *(const float4*)&x[(size_t)b * CD + t * 4];
            *(float4*)&xo[(size_t)b * CD + t * 4] = v;
            fg[(size_t)b * FGD + t * 4 + 0] = v.x;
            fg[(size_t)b * FGD + t * 4 + 1] = v.y;
            fg[(size_t)b * FGD + t * 4 + 2] = v.z;
            fg[(size_t)b * FGD + t * 4 + 3] = v.w;
            us4 hh, ff;
            float* vp = (float*)&v;
#pragma unroll
            for (int k = 0; k < 4; ++k) {
                ((ushortT*)&hh)[k] = f2bf(vp[k]);
                _Float16 g = (_Float16)vp[k];
                ((ushortT*)&ff)[k] = *(ushortT*)&g;
            }
            *(us4*)&xh[(size_t)b * CD + t * 4] = hh;
            *(us4*)&xf[(size_t)b * CD + t * 4] = ff;
        }
        return;
    }
    if (b >= 4512) {
        // ---- gsum branch: per-label fp64 column sums (16 rows/block) ----
        int bb = b - 4512;
        int t = threadIdx.x;
        double a0[3] = {0, 0, 0}, a1[3] = {0, 0, 0};
        for (int rr = 0; rr < 16; ++rr) {
            int row = bb * 16 + rr;
            int lab = labels[row];
#pragma unroll
            for (int s = 0; s < 3; ++s) {
                double v = (double)x[(size_t)row * CD + t + s * 256];
                if (lab == 0) a0[s] += v; else a1[s] += v;
            }
        }
#pragma unroll
        for (int s = 0; s < 3; ++s) {
            atomicAdd(&gsum[t + s * 256], a0[s]);
            atomicAdd(&gsum[768 + t + s * 256], a1[s]);
        }
        return;
    }
    __shared__ float tT[32][33];
    const float* P;
    ushortT* T;
    int K, N, Npad, k0, n0;
    if (b < 4480) {
        int bb = b - 4096;
        P = W1; T = w1t; K = CD; N = HD; Npad = HD;
        k0 = (bb % 24) * 32; n0 = (bb / 24) * 32;
    } else {
        int bb = b - 4480;
        P = W2; T = w2t; K = HD; N = OD; Npad = 64;
        k0 = (bb % 16) * 32; n0 = (bb / 16) * 32;
    }
    int tx = threadIdx.x & 31, ty = threadIdx.x >> 5;
#pragma unroll
    for (int s = 0; s < 4; ++s) {
        int k = k0 + ty + s * 8, n = n0 + tx;
        tT[ty + s * 8][tx] = (k < K && n < N) ? P[(size_t)k * N + n] : 0.0f;
    }
    __syncthreads();
#pragma unroll
    for (int s = 0; s < 4; ++s) {
        int n = n0 + ty + s * 8, k = k0 + tx;
        if (n < Npad && k < K) T[(size_t)n * K + k] = f2bf(tT[tx][ty + s * 8]);
    }
}

// ---------------------------------------------------------------------------
// Split-K partial GEMM (N=64, bf16 A): P[kb][row][64]; grid (KS, M/64). (K6)
// ---------------------------------------------------------------------------
__global__ __launch_bounds__(256) void gemm_part(
    const ushortT* __restrict__ A, const ushortT* __restrict__ B,
    float* __restrict__ P, int M, int K, int KC) {
    __shared__ ushortT lds[2 * 64 * 72];
    int tid = threadIdx.x;
    int lane = tid & 63;
    int w = tid >> 6;
    int wr = w >> 1, wc = w & 1;
    int m = lane & 15, quad = lane >> 4;
    int kb = blockIdx.x;
    int row0 = blockIdx.y * 64;
    int kbase = kb * KC;

    f32x4 acc[2][2] = {{{0.f, 0.f, 0.f, 0.f}, {0.f, 0.f, 0.f, 0.f}},
                       {{0.f, 0.f, 0.f, 0.f}, {0.f, 0.f, 0.f, 0.f}}};

    for (int k0 = 0; k0 < KC; k0 += 64) {
#pragma unroll
        for (int t = 0; t < 2; ++t) {
            int id2 = tid + t * 256;
            int row = id2 >> 3, c8 = (id2 & 7) * 8;
            *(short8*)&lds[row * 72 + c8] =
                *(const short8*)&A[(size_t)(row0 + row) * K + kbase + k0 + c8];
            *(short8*)&lds[4608 + row * 72 + c8] =
                *(const short8*)&B[(size_t)row * K + kbase + k0 + c8];
        }
        __syncthreads();
#pragma unroll
        for (int ks = 0; ks < 2; ++ks) {
            short8 af[2], bf[2];
#pragma unroll
            for (int i = 0; i < 2; ++i)
                af[i] = *(const short8*)&lds[(wr * 32 + i * 16 + m) * 72 +
                                             ks * 32 + quad * 8];
#pragma unroll
            for (int j = 0; j < 2; ++j)
                bf[j] = *(const short8*)&lds[4608 + (wc * 32 + j * 16 + m) * 72 +
                                             ks * 32 + quad * 8];
#pragma unroll
            for (int i = 0; i < 2; ++i)
#pragma unroll
                for (int j = 0; j < 2; ++j)
                    acc[i][j] = __builtin_amdgcn_mfma_f32_16x16x32_bf16(
                        af[i], bf[j], acc[i][j], 0, 0, 0);
        }
        __syncthreads();
    }
#pragma unroll
    for (int i = 0; i < 2; ++i)
#pragma unroll
        for (int j = 0; j < 2; ++j)
#pragma unroll
            for (int r = 0; r < 4; ++r) {
                int row = wr * 32 + i * 16 + quad * 4 + r;
                int col = wc * 32 + j * 16 + m;
                P[((size_t)kb * M + row0 + row) * 64 + col] = acc[i][j][r];
            }
}

// ---------------------------------------------------------------------------
// Split-K partial GEMM (N=64, BIT A): A tile expanded from packed adjacency
// bits in LDS — no bf16 A in HBM. (K7)
// ---------------------------------------------------------------------------
__global__ __launch_bounds__(256) void gemm_partB(
    const u64* __restrict__ Abits, const ushortT* __restrict__ B,
    float* __restrict__ P, int M, int K, int KC) {
    __shared__ ushortT lds[2 * 64 * 72];
    int tid = threadIdx.x;
    int lane = tid & 63;
    int w = tid >> 6;
    int wr = w >> 1, wc = w & 1;
    int m = lane & 15, quad = lane >> 4;
    int kb = blockIdx.x;
    int row0 = blockIdx.y * 64;
    int kbase = kb * KC;
    int er = tid >> 2, eq = tid & 3;

    f32x4 acc[2][2] = {{{0.f, 0.f, 0.f, 0.f}, {0.f, 0.f, 0.f, 0.f}},
                       {{0.f, 0.f, 0.f, 0.f}, {0.f, 0.f, 0.f, 0.f}}};

    for (int k0 = 0; k0 < KC; k0 += 64) {
#pragma unroll
        for (int t = 0; t < 2; ++t) {
            int id2 = tid + t * 256;
            int row = id2 >> 3, c8 = (id2 & 7) * 8;
            *(short8*)&lds[4608 + row * 72 + c8] =
                *(const short8*)&B[(size_t)row * K + kbase + k0 + c8];
        }
        {
            u64 bits = Abits[(size_t)(row0 + er) * 64 + ((kbase + k0) >> 6)];
            unsigned int half = (unsigned int)(bits >> (eq * 16)) & 0xFFFFu;
            short8 v0, v1;
#pragma unroll
            for (int k = 0; k < 8; ++k) {
                ((ushortT*)&v0)[k] =
                    ((half >> k) & 1) ? (ushortT)0x3F80 : (ushortT)0;
                ((ushortT*)&v1)[k] =
                    ((half >> (k + 8)) & 1) ? (ushortT)0x3F80 : (ushortT)0;
            }
            *(short8*)&lds[er * 72 + eq * 16] = v0;
            *(short8*)&lds[er * 72 + eq * 16 + 8] = v1;
        }
        __syncthreads();
#pragma unroll
        for (int ks = 0; ks < 2; ++ks) {
            short8 af[2], bf[2];
#pragma unroll
            for (int i = 0; i < 2; ++i)
                af[i] = *(const short8*)&lds[(wr * 32 + i * 16 + m) * 72 +
                                             ks * 32 + quad * 8];
#pragma unroll
            for (int j = 0; j < 2; ++j)
                bf[j] = *(const short8*)&lds[4608 + (wc * 32 + j * 16 + m) * 72 +
                                             ks * 32 + quad * 8];
#pragma unroll
            for (int i = 0; i < 2; ++i)
#pragma unroll
                for (int j = 0; j < 2; ++j)
                    acc[i][j] = __builtin_amdgcn_mfma_f32_16x16x32_bf16(
                        af[i], bf[j], acc[i][j], 0, 0, 0);
        }
        __syncthreads();
    }
#pragma unroll
    for (int i = 0; i < 2; ++i)
#pragma unroll
        for (int j = 0; j < 2; ++j)
#pragma unroll
            for (int r = 0; r < 4; ++r) {
                int row = wr * 32 + i * 16 + quad * 4 + r;
                int col = wc * 32 + j * 16 + m;
                P[((size_t)kb * M + row0 + row) * 64 + col] = acc[i][j][r];
            }
}

// ---------------------------------------------------------------------------
// Split-K WIDE partial GEMM (BIT A, f32 B with fused dinv scaling), R12-
// proven: M-tile 128, grid (HD/64, NN/128, 4). Per wave 32x64 via acc[2][4].
// ---------------------------------------------------------------------------
__global__ __launch_bounds__(256) void gemm_partWB(
    const u64* __restrict__ Abits, const float* __restrict__ Bf,
    const int* __restrict__ deg, float* __restrict__ P,
    int M, int K, int KC, int ldP) {
    __shared__ ushortT lds[192 * 72];           // A:[0,128*72) B:[128*72,...)
    __shared__ float dinvK[1024];               // KC <= 1024
    const int BO = 128 * 72;
    int tid = threadIdx.x;
    int lane = tid & 63;
    int w = tid >> 6;                           // wave 0..3 -> rows w*32..+32
    int m = lane & 15, quad = lane >> 4;
    int col0 = blockIdx.x * 64;
    int row0 = blockIdx.y * 128;
    int kb = blockIdx.z;
    int kbase = kb * KC;
    int er = tid >> 1, eq = tid & 1;            // 128 rows x 2 half-u64s

    for (int v = tid; v < KC; v += 256)
        dinvK[v] = 1.0f / sqrtf((float)(1 + deg[kbase + v]));
    __syncthreads();

    f32x4 acc[2][4];
#pragma unroll
    for (int i = 0; i < 2; ++i)
#pragma unroll
        for (int j = 0; j < 4; ++j) acc[i][j] = {0.f, 0.f, 0.f, 0.f};

    for (int k0 = 0; k0 < KC; k0 += 64) {
        // B stage: 64 cols x 64 K, f32 -> bf16 with dinv scale
#pragma unroll
        for (int t = 0; t < 2; ++t) {
            int id2 = tid + t * 256;
            int row = id2 >> 3, c8 = (id2 & 7) * 8;
            const float* bp = &Bf[(size_t)(col0 + row) * K + kbase + k0 + c8];
            float4 v0 = *(const float4*)bp;
            float4 v1 = *(const float4*)(bp + 4);
            short8 o;
            ((ushortT*)&o)[0] = f2bf(v0.x * dinvK[k0 + c8 + 0]);
            ((ushortT*)&o)[1] = f2bf(v0.y * dinvK[k0 + c8 + 1]);
            ((ushortT*)&o)[2] = f2bf(v0.z * dinvK[k0 + c8 + 2]);
            ((ushortT*)&o)[3] = f2bf(v0.w * dinvK[k0 + c8 + 3]);
            ((ushortT*)&o)[4] = f2bf(v1.x * dinvK[k0 + c8 + 4]);
            ((ushortT*)&o)[5] = f2bf(v1.y * dinvK[k0 + c8 + 5]);
            ((ushortT*)&o)[6] = f2bf(v1.z * dinvK[k0 + c8 + 6]);
            ((ushortT*)&o)[7] = f2bf(v1.w * dinvK[k0 + c8 + 7]);
            *(short8*)&lds[BO + row * 72 + c8] = o;
        }
        // A stage: 128 rows of packed bits; each thread expands 32 bits
        {
            u64 bits = Abits[(size_t)(row0 + er) * 64 + ((kbase + k0) >> 6)];
            unsigned int hf = (unsigned int)(bits >> (eq * 32));
            short8 v0, v1, v2, v3;
#pragma unroll
            for (int k = 0; k < 8; ++k) {
                ((ushortT*)&v0)[k] = ((hf >> k) & 1) ? (ushortT)0x3F80 : (ushortT)0;
                ((ushortT*)&v1)[k] = ((hf >> (k + 8)) & 1) ? (ushortT)0x3F80 : (ushortT)0;
                ((ushortT*)&v2)[k] = ((hf >> (k + 16)) & 1) ? (ushortT)0x3F80 : (ushortT)0;
                ((ushortT*)&v3)[k] = ((hf >> (k + 24)) & 1) ? (ushortT)0x3F80 : (ushortT)0;
            }
            int ab = er * 72 + eq * 32;
            *(short8*)&lds[ab + 0] = v0;
            *(short8*)&lds[ab + 8] = v1;
            *(short8*)&lds[ab + 16] = v2;
            *(short8*)&lds[ab + 24] = v3;
        }
        __syncthreads();
#pragma unroll
        for (int ks = 0; ks < 2; ++ks) {
            short8 af[2], bf[4];
#pragma unroll
            for (int i = 0; i < 2; ++i)
                af[i] = *(const short8*)&lds[(w * 32 + i * 16 + m) * 72 +
                                             ks * 32 + quad * 8];
#pragma unroll
            for (int j = 0; j < 4; ++j)
                bf[j] = *(const short8*)&lds[BO + (j * 16 + m) * 72 +
                                             ks * 32 + quad * 8];
#pragma unroll
            for (int i = 0; i < 2; ++i)
#pragma unroll
                for (int j = 0; j < 4; ++j)
                    acc[i][j] = __builtin_amdgcn_mfma_f32_16x16x32_bf16(
                        af[i], bf[j], acc[i][j], 0, 0, 0);
        }
        __syncthreads();
    }
#pragma unroll
    for (int i = 0; i < 2; ++i)
#pragma unroll
        for (int j = 0; j < 4; ++j)
#pragma unroll
            for (int r = 0; r < 4; ++r) {
                int row = row0 + w * 32 + i * 16 + quad * 4 + r;
                int col = col0 + j * 16 + m;
                P[((size_t)kb * M + row) * ldP + col] = acc[i][j][r];
            }
}

// ---------------------------------------------------------------------------
// k5 epilogue: hb[r][c] = bf16(relu(dinv[r]*sum_kb P5[kb][r][c] + b1[c])).
// SK=4.
// ---------------------------------------------------------------------------
__global__ __launch_bounds__(256) void k5_epi(const float* __restrict__ P5,
                                              const int* __restrict__ deg,
                                              const float* __restrict__ b1,
                                              ushortT* __restrict__ hb) {
    int tid = threadIdx.x;
    int cg = tid & 127;      // 128 groups of float4 = 512 cols
    int rr = tid >> 7;       // 0..1
#pragma unroll
    for (int p = 0; p < 2; ++p) {
        int r = blockIdx.x * 4 + p * 2 + rr;
        float dv = dinv_of(deg[r]);
        float4 s = {0.f, 0.f, 0.f, 0.f};
#pragma unroll
        for (int kb = 0; kb < 4; ++kb) {
            float4 v = *(const float4*)&P5[((size_t)kb * NN + r) * HD + cg * 4];
            s.x += v.x; s.y += v.y; s.z += v.z; s.w += v.w;
        }
        float4 bv = *(const float4*)&b1[cg * 4];
        us4 o;
        o[0] = f2bf(fmaxf(s.x * dv + bv.x, 0.f));
        o[1] = f2bf(fmaxf(s.y * dv + bv.y, 0.f));
        o[2] = f2bf(fmaxf(s.z * dv + bv.z, 0.f));
        o[3] = f2bf(fmaxf(s.w * dv + bv.w, 0.f));
        *(us4*)&hb[(size_t)r * HD + cg * 4] = o;
    }
}

// ---------------------------------------------------------------------------
// k6 epilogue: hw2sT[c][r] = bf16(dinv[r] * sum_kb P6[kb][r][c]); 64 blocks.
// ---------------------------------------------------------------------------
__global__ __launch_bounds__(256) void k6_epi(const float* __restrict__ P6,
                                              const int* __restrict__ deg,
                                              ushortT* __restrict__ hw2sT) {
    __shared__ ushortT Th[64 * 72];
    int row0 = blockIdx.x * 64;
    int tid = threadIdx.x;
    int rl = tid >> 2, q = tid & 3;
    float dv = dinv_of(deg[row0 + rl]);
#pragma unroll
    for (int s = 0; s < 16; ++s) {
        int c = q * 16 + s;
        float v = 0.f;
#pragma unroll
        for (int kb = 0; kb < 8; ++kb)
            v += P6[((size_t)kb * NN + row0 + rl) * 64 + c];
        Th[c * 72 + rl] = f2bf(v * dv);
    }
    __syncthreads();
#pragma unroll
    for (int t = 0; t < 2; ++t) {
        int id2 = tid + t * 256;
        int cc = id2 >> 3, chunk = id2 & 7;
        *(short8*)&hw2sT[(size_t)cc * NN + row0 + chunk * 8] =
            *(const short8*)&Th[cc * 72 + chunk * 8];
    }
}

// ---------------------------------------------------------------------------
// k7 epilogue + final fc: writes g into f_g AND computes out[r].
// ---------------------------------------------------------------------------
__global__ __launch_bounds__(256) void k7_epi_out(
    const float* __restrict__ P7, const int* __restrict__ deg,
    const float* __restrict__ b2, const float* __restrict__ fcW,
    const float* __restrict__ fcb, float* __restrict__ fg,
    float* __restrict__ out) {
    int row0 = blockIdx.x * 64;
    int tid = threadIdx.x;
    int rl = tid >> 2, q = tid & 3;
    int r = row0 + rl;
    float dv = dinv_of(deg[r]);
    float sg = 0.f;
#pragma unroll
    for (int s = 0; s < 16; ++s) {
        int c = q * 16 + s;
        if (c < OD) {
            float v = 0.f;
#pragma unroll
            for (int kb = 0; kb < 16; ++kb)
                v += P7[((size_t)kb * NN + r) * 64 + c];
            v = v * dv + b2[c];
            fg[(size_t)r * FGD + CD + c] = v;
            sg += v * fcW[CD + c];
        }
    }
    // x-part dot (f_g rows are 8B-aligned: use float2)
    const float* fr = fg + (size_t)r * FGD;
    float sx = 0.f;
    for (int k = q * 192; k < (q + 1) * 192; k += 2) {
        float2 vv = *(const float2*)&fr[k];
        float2 ww = *(const float2*)&fcW[k];
        sx += vv.x * ww.x + vv.y * ww.y;
    }
    float s = sx + sg;
    s += __shfl_down(s, 1);
    s += __shfl_down(s, 2);
    if (q == 0) out[r] = s + fcb[0];
}

extern "C" void kernel_launch(void* const* d_in, const int* in_sizes, int n_in,
                              void* d_out, int out_size, void* d_ws, size_t ws_size,
                              hipStream_t stream) {
    const float* x = (const float*)d_in[0];
    const int* labels = (const int*)d_in[1];
    const float* W1 = (const float*)d_in[2];
    const float* b1 = (const float*)d_in[3];
    const float* W2 = (const float*)d_in[4];
    const float* b2 = (const float*)d_in[5];
    const float* fcW = (const float*)d_in[6];
    const float* fcb = (const float*)d_in[7];
    float* outp = (float*)d_out;

    const size_t o_out = 0;
    const size_t o_fg = 4096;
    const size_t o_lm = o_fg + (size_t)NN * FGD;
    const size_t o_x = o_lm + (size_t)NN * NN;

    // workspace layout (R12-proven)
    char* ws = (char*)d_ws;
    size_t off = 0;
    u64* abbits = (u64*)(ws + off); off += (size_t)NN * 64 * 8;          // 2 MiB
    ushortT* xh = (ushortT*)(ws + off); off += (size_t)NN * CD * 2;
    ushortT* xf = (ushortT*)(ws + off); off += (size_t)NN * CD * 2;      // f16
    ushortT* w1t = (ushortT*)(ws + off); off += (size_t)HD * CD * 2;
    float* xw1f = (float*)(ws + off); off += (size_t)HD * NN * 4;        // 8 MiB
    ushortT* hb = (ushortT*)(ws + off); off += (size_t)NN * HD * 2;      // 4 MiB
    ushortT* w2t = (ushortT*)(ws + off); off += (size_t)64 * HD * 2;
    ushortT* hw2sT = (ushortT*)(ws + off); off += (size_t)64 * NN * 2;
    char* zbase = ws + off;
    int* deg = (int*)(ws + off); off += (size_t)NN * 4;
    double* gsum = (double*)(ws + off); off += 1536 * 8;
    double* scal = (double*)(ws + off); off += 16;
    int* rc_cnt = (int*)(ws + off); off += 16;
    size_t zbytes = (size_t)NN * 4 + 1536 * 8 + 16 + 16;
    // UNION region: rc_list (1 MiB) -> P5 (32 MiB, SK=4) -> P6 (8 MiB) ->
    // P7 (16 MiB); strictly sequential lifetimes. xw1f OUTSIDE the union.
    char* uni = ws + off;
    int* rc_list = (int*)uni;                       // 1 MiB
    float* P5 = (float*)uni;                        // 32 MiB (4*NN*HD*4)
    float* P6 = (float*)uni;                        // 8 MiB  (8*NN*64*4)
    float* P7 = (float*)uni;                        // 16 MiB (16*NN*64*4)
    off += (size_t)4 * NN * HD * 4;

    hipMemsetAsync(zbase, 0, zbytes, stream);

    // prep (x casts + weight transposes) FUSED with gsum (4768 blocks)
    prep_kernel<<<4768, 256, 0, stream>>>(x, W1, W2, labels, outp + o_fg,
                                          outp + o_x, xh, xf, w1t, w2t, gsum);

    // threshold scalars
    gdot_kernel<<<1, 256, 0, stream>>>(gsum, labels, scal);

    // sim (f16, XOR-swizzled LDS, packed bits) FUSED with K4 (f32 x@W1^T)
    simk4<<<2592, 256, 0, stream>>>(xf, xh, w1t, labels, scal, abbits,
                                    outp + o_lm, deg, rc_cnt, rc_list, xw1f);

    // exact fp64 resolution of band entries (one wave per entry)
    rc_fix<<<512, 256, 0, stream>>>(x, scal, rc_cnt, rc_list, abbits, outp + o_lm,
                                    deg);

    // K5: split-K (SK=4), M-tile 128, bit-A expansion + fused dinv scaling
    gemm_partWB<<<dim3(HD / 64, NN / 128, 4), 256, 0, stream>>>(
        abbits, xw1f, deg, P5, NN, NN, NN / 4, HD);
    k5_epi<<<NN / 4, 256, 0, stream>>>(P5, deg, b1, hb);

    // K6: hw2sT via split-K (SK=8) partials + epilogue
    gemm_part<<<dim3(8, NN / 64), 256, 0, stream>>>(hb, w2t, P6, NN, HD, HD / 8);
    k6_epi<<<NN / 64, 256, 0, stream>>>(P6, deg, hw2sT);

    // K7: g via split-K (SK=16) partials (bit-A) + fused epilogue/out
    gemm_partB<<<dim3(16, NN / 64), 256, 0, stream>>>(abbits, hw2sT, P7, NN, NN,
                                                      NN / 16);
    k7_epi_out<<<NN / 64, 256, 0, stream>>>(P7, deg, b2, fcW, fcb, outp + o_fg,
                                            outp + o_out);
}